// Round 1
// baseline (822.567 us; speedup 1.0000x reference)
//
#include <hip/hip_runtime.h>
#include <math.h>

#define S_TOK 2048
#define HID   2048
#define FFN_  2048
#define NEXP  8
#define NSLOT (S_TOK*2)

typedef short  s8v __attribute__((ext_vector_type(8)));
typedef short  s4v __attribute__((ext_vector_type(4)));
typedef float  f4v __attribute__((ext_vector_type(4)));

__device__ __forceinline__ unsigned short f32_bf16(float f){
  unsigned u = __float_as_uint(f);
  u += 0x7fffu + ((u>>16)&1u);          // RNE
  return (unsigned short)(u>>16);
}
// swizzled LDS layout: element (r,k) lives in 8-short slot (r*4 + ((k>>3) ^ ((r>>2)&3)))
// -> b128 fragment reads conflict-free, transposed staging writes ~4-way.
__device__ __forceinline__ int lds_off(int r,int kq){
  return (r*4 + (kq ^ ((r>>2)&3)))*8;
}

// ---------------- init: zero counts/cursors/offs ----------------
__global__ void init_k(int* hdr){
  if (threadIdx.x < 24) hdr[threadIdx.x] = 0;
}

// ---------------- router: one wave per token, all fp32 ----------------
__global__ __launch_bounds__(64) void router_k(
    const float* __restrict__ X, const float* __restrict__ Wqkv,
    int* __restrict__ hdr, int* __restrict__ idx, float* __restrict__ scr)
{
  const int s = blockIdx.x, lane = threadIdx.x;
  const float* x = X + (size_t)s*HID;
  f4v xv[8];
  #pragma unroll
  for (int i=0;i<8;i++) xv[i] = *reinterpret_cast<const f4v*>(x + (i*64+lane)*4);
  float dot[24];
  #pragma unroll
  for (int o=0;o<24;o++){
    const float* w = Wqkv + (size_t)o*HID;
    float a = 0.f;
    #pragma unroll
    for (int i=0;i<8;i++){
      f4v wv = *reinterpret_cast<const f4v*>(w + (i*64+lane)*4);
      a += xv[i][0]*wv[0] + xv[i][1]*wv[1] + xv[i][2]*wv[2] + xv[i][3]*wv[3];
    }
    #pragma unroll
    for (int off=32; off; off>>=1) a += __shfl_xor(a, off, 64);
    dot[o] = a;
  }
  if (lane==0){
    float lg[8];
    #pragma unroll
    for (int i=0;i<8;i++){
      float qi = dot[i];
      float mx = -1e30f;
      #pragma unroll
      for (int j=0;j<8;j++) mx = fmaxf(mx, qi*dot[8+j]);
      float se=0.f, lv=0.f;
      #pragma unroll
      for (int j=0;j<8;j++){
        float e = expf(qi*dot[8+j] - mx);
        se += e; lv += e*dot[16+j];
      }
      lg[i] = lv/se;
    }
    int i0=0; float v0=lg[0];
    #pragma unroll
    for (int i=1;i<8;i++) if (lg[i]>v0){v0=lg[i];i0=i;}
    int i1=-1; float v1=-1e30f;
    #pragma unroll
    for (int i=0;i<8;i++) if (i!=i0 && lg[i]>v1){v1=lg[i];i1=i;}
    float a  = expf(v1-v0);
    float s0 = 1.f/(1.f+a);
    idx[s*2]=i0; idx[s*2+1]=i1;
    scr[s*2]=s0; scr[s*2+1]=a*s0;
    atomicAdd(&hdr[i0],1); atomicAdd(&hdr[i1],1);
  }
}

// ---------------- scan: exclusive prefix of 8 counts ----------------
__global__ void scan_k(int* hdr){
  if (threadIdx.x==0){
    int a=0;
    for (int e=0;e<NEXP;e++){ hdr[16+e]=a; a+=hdr[e]; }
  }
}

// ---------------- scatter: assign slots ----------------
__global__ __launch_bounds__(256) void scatter_k(
    const int* __restrict__ idx, const float* __restrict__ scr, int* hdr,
    int* __restrict__ slot_of, int* __restrict__ tok_slot, float* __restrict__ scr_slot)
{
  int s = blockIdx.x*256 + threadIdx.x;
  if (s >= S_TOK) return;
  #pragma unroll
  for (int k=0;k<2;k++){
    int e    = idx[s*2+k];
    int pos  = atomicAdd(&hdr[8+e], 1);
    int slot = hdr[16+e] + pos;
    tok_slot[slot] = s;
    scr_slot[slot] = scr[s*2+k];
    slot_of[s*2+k] = slot;
  }
}

// ---------------- grouped GEMM1: inter = silu(X W1g) * (X W1u) ----------------
// grid (FFN/64, S/128, E), block 256. Tile M=128, 64 j-cols => 128 acc cols (g+u).
__global__ __launch_bounds__(256,2) void gemm1_k(
    const float* __restrict__ X, const float* __restrict__ W1,
    const int* __restrict__ hdr, const int* __restrict__ tok_slot,
    unsigned short* __restrict__ inter)
{
  const int e = blockIdx.z, mt = blockIdx.y, nt = blockIdx.x;
  const int cnt = hdr[e];
  const int m0  = mt*128;
  if (m0 >= cnt) return;
  const int off = hdr[16+e];
  const int n0  = nt*64;
  const float* W1e = W1 + (size_t)e*HID*(2*FFN_);

  __shared__ __align__(16) unsigned short sA[128*32];
  __shared__ __align__(16) unsigned short sB[128*32];
  __shared__ int sTok[128];

  const int tid = threadIdx.x;
  if (tid < 128){
    int r = m0 + tid; if (r >= cnt) r = cnt-1;
    sTok[tid] = tok_slot[off + r];
  }
  const int lane = tid & 63, wv = tid >> 6;
  const int wm = wv >> 1, wn = wv & 1;
  const int lm = lane & 15, kq = lane >> 4;
  const int b_cq = tid & 31, b_k4 = tid >> 5;
  const int b_j  = (b_cq<16) ? (n0 + b_cq*4) : (FFN_ + n0 + (b_cq-16)*4);
  const int b_n  = b_cq*4;

  f4v zero = {0.f,0.f,0.f,0.f};
  f4v acc[2][2][4];
  #pragma unroll
  for (int a=0;a<2;a++)
    #pragma unroll
    for (int b=0;b<2;b++)
      #pragma unroll
      for (int c=0;c<4;c++) acc[a][b][c]=zero;

  __syncthreads();

  for (int k0=0; k0<HID; k0+=32){
    // stage A: gathered token rows, fp32 -> bf16
    #pragma unroll
    for (int i=0;i<4;i++){
      int v = tid + i*256;
      int m = v>>3, c4q = v&7;
      f4v f = *reinterpret_cast<const f4v*>(X + (size_t)sTok[m]*HID + k0 + c4q*4);
      s4v p; p[0]=(short)f32_bf16(f[0]); p[1]=(short)f32_bf16(f[1]);
             p[2]=(short)f32_bf16(f[2]); p[3]=(short)f32_bf16(f[3]);
      *reinterpret_cast<s4v*>(&sA[lds_off(m, c4q>>1) + (c4q&1)*4]) = p;
    }
    // stage B: 4 k-rows x 4 j, register transpose, fp32 -> bf16, [n][k] layout
    f4v bw[4];
    #pragma unroll
    for (int kk=0;kk<4;kk++)
      bw[kk] = *reinterpret_cast<const f4v*>(W1e + (size_t)(k0 + b_k4*4 + kk)*(2*FFN_) + b_j);
    #pragma unroll
    for (int jj=0;jj<4;jj++){
      int n = b_n + jj;
      s4v p; p[0]=(short)f32_bf16(bw[0][jj]); p[1]=(short)f32_bf16(bw[1][jj]);
             p[2]=(short)f32_bf16(bw[2][jj]); p[3]=(short)f32_bf16(bw[3][jj]);
      *reinterpret_cast<s4v*>(&sB[lds_off(n, b_k4>>1) + (b_k4&1)*4]) = p;
    }
    __syncthreads();
    s8v af[4], bf_[2][2];
    #pragma unroll
    for (int mf=0;mf<4;mf++)
      af[mf] = *reinterpret_cast<const s8v*>(&sA[lds_off(wm*64+mf*16+lm, kq)]);
    #pragma unroll
    for (int st=0; st<2; st++)
      #pragma unroll
      for (int nf=0;nf<2;nf++)
        bf_[st][nf] = *reinterpret_cast<const s8v*>(&sB[lds_off(st*64+wn*32+nf*16+lm, kq)]);
    #pragma unroll
    for (int st=0; st<2; st++)
      #pragma unroll
      for (int nf=0;nf<2;nf++)
        #pragma unroll
        for (int mf=0;mf<4;mf++)
          acc[st][nf][mf] = __builtin_amdgcn_mfma_f32_16x16x32_bf16(
              af[mf], bf_[st][nf], acc[st][nf][mf], 0,0,0);
    __syncthreads();
  }
  // epilogue: silu(g)*u -> bf16 inter
  const int lq = lane>>4;
  #pragma unroll
  for (int nf=0;nf<2;nf++)
    #pragma unroll
    for (int mf=0;mf<4;mf++){
      f4v g = acc[0][nf][mf], u = acc[1][nf][mf];
      #pragma unroll
      for (int r=0;r<4;r++){
        int row = wm*64 + mf*16 + lq*4 + r;
        if (m0+row < cnt){
          float gv = g[r];
          float val = gv / (1.f + expf(-gv)) * u[r];
          inter[(size_t)(off+m0+row)*FFN_ + n0 + wn*32 + nf*16 + lm] = f32_bf16(val);
        }
      }
    }
}

// ---------------- grouped GEMM2: eout = score * (inter @ W2) ----------------
// grid (HID/128, S/128, E), block 256.
__global__ __launch_bounds__(256,2) void gemm2_k(
    const unsigned short* __restrict__ inter, const float* __restrict__ W2,
    const int* __restrict__ hdr, const float* __restrict__ scr_slot,
    float* __restrict__ eout)
{
  const int e = blockIdx.z, mt = blockIdx.y, nt = blockIdx.x;
  const int cnt = hdr[e];
  const int m0  = mt*128;
  if (m0 >= cnt) return;
  const int off = hdr[16+e];
  const int n0  = nt*128;
  const float* W2e = W2 + (size_t)e*FFN_*HID;

  __shared__ __align__(16) unsigned short sA[128*32];
  __shared__ __align__(16) unsigned short sB[128*32];
  __shared__ float sScr[128];

  const int tid = threadIdx.x;
  if (tid < 128){
    int r = m0 + tid; if (r >= cnt) r = cnt-1;
    sScr[tid] = scr_slot[off + r];
  }
  const int lane = tid & 63, wv = tid >> 6;
  const int wm = wv >> 1, wn = wv & 1;
  const int lm = lane & 15, kq = lane >> 4;
  const int b_cq = tid & 31, b_k4 = tid >> 5;
  const int b_j  = n0 + b_cq*4;
  const int b_n  = b_cq*4;

  f4v zero = {0.f,0.f,0.f,0.f};
  f4v acc[4][4];
  #pragma unroll
  for (int a=0;a<4;a++)
    #pragma unroll
    for (int b=0;b<4;b++) acc[a][b]=zero;

  __syncthreads();

  for (int k0=0; k0<FFN_; k0+=32){
    // stage A: inter rows already bf16, straight 16B copies
    #pragma unroll
    for (int i=0;i<2;i++){
      int v = tid + i*256;            // [0,512)
      int m = v>>2, kk8 = v&3;
      int r = m0+m; if (r>=cnt) r = cnt-1;
      s8v a = *reinterpret_cast<const s8v*>(inter + (size_t)(off+r)*FFN_ + k0 + kk8*8);
      *reinterpret_cast<s8v*>(&sA[lds_off(m, kk8)]) = a;
    }
    // stage B: W2 fp32 -> bf16, register transpose
    f4v bw[4];
    #pragma unroll
    for (int kk=0;kk<4;kk++)
      bw[kk] = *reinterpret_cast<const f4v*>(W2e + (size_t)(k0 + b_k4*4 + kk)*HID + b_j);
    #pragma unroll
    for (int jj=0;jj<4;jj++){
      int n = b_n + jj;
      s4v p; p[0]=(short)f32_bf16(bw[0][jj]); p[1]=(short)f32_bf16(bw[1][jj]);
             p[2]=(short)f32_bf16(bw[2][jj]); p[3]=(short)f32_bf16(bw[3][jj]);
      *reinterpret_cast<s4v*>(&sB[lds_off(n, b_k4>>1) + (b_k4&1)*4]) = p;
    }
    __syncthreads();
    s8v af[4], bf_[4];
    #pragma unroll
    for (int mf=0;mf<4;mf++)
      af[mf] = *reinterpret_cast<const s8v*>(&sA[lds_off(wm*64+mf*16+lm, kq)]);
    #pragma unroll
    for (int nf=0;nf<4;nf++)
      bf_[nf] = *reinterpret_cast<const s8v*>(&sB[lds_off(wn*64+nf*16+lm, kq)]);
    #pragma unroll
    for (int nf=0;nf<4;nf++)
      #pragma unroll
      for (int mf=0;mf<4;mf++)
        acc[nf][mf] = __builtin_amdgcn_mfma_f32_16x16x32_bf16(
            af[mf], bf_[nf], acc[nf][mf], 0,0,0);
    __syncthreads();
  }
  const int lq = lane>>4;
  #pragma unroll
  for (int nf=0;nf<4;nf++)
    #pragma unroll
    for (int mf=0;mf<4;mf++)
      #pragma unroll
      for (int r=0;r<4;r++){
        int row = wm*64 + mf*16 + lq*4 + r;
        if (m0+row < cnt)
          eout[(size_t)(off+m0+row)*HID + n0 + wn*64 + nf*16 + lm] = acc[nf][mf][r]*sScr[row];
      }
}

// ---------------- combine: out[s] = eout[slot0] + eout[slot1] ----------------
__global__ __launch_bounds__(256) void combine_k(
    const float* __restrict__ eout, const int* __restrict__ slot_of,
    float* __restrict__ out)
{
  int s = blockIdx.x, tid = threadIdx.x;
  const float* a = eout + (size_t)slot_of[s*2]  *HID;
  const float* b = eout + (size_t)slot_of[s*2+1]*HID;
  float* o = out + (size_t)s*HID;
  #pragma unroll
  for (int v=tid; v<HID/4; v+=256){
    f4v x = *reinterpret_cast<const f4v*>(a + v*4);
    f4v y = *reinterpret_cast<const f4v*>(b + v*4);
    *reinterpret_cast<f4v*>(o + v*4) = x + y;
  }
}

extern "C" void kernel_launch(void* const* d_in, const int* in_sizes, int n_in,
                              void* d_out, int out_size, void* d_ws, size_t ws_size,
                              hipStream_t stream)
{
  const float* X    = (const float*)d_in[0];
  const float* Wqkv = (const float*)d_in[1];
  const float* W1   = (const float*)d_in[2];
  const float* W2   = (const float*)d_in[3];
  float* out = (float*)d_out;

  char* ws = (char*)d_ws;
  int*   hdr      = (int*)ws;                       // counts[8], cursor[8], offs[8]
  int*   idx      = (int*)(ws + 256);
  float* scr      = (float*)(ws + 256 + 1*16384);
  int*   slot_of  = (int*)(ws + 256 + 2*16384);
  int*   tok_slot = (int*)(ws + 256 + 3*16384);
  float* scr_slot = (float*)(ws + 256 + 4*16384);
  unsigned short* inter = (unsigned short*)(ws + 82176);
  float* eout     = (float*)(ws + 82176 + (size_t)NSLOT*FFN_*2);

  init_k   <<<1,   64, 0, stream>>>(hdr);
  router_k <<<S_TOK,64,0, stream>>>(X, Wqkv, hdr, idx, scr);
  scan_k   <<<1,   64, 0, stream>>>(hdr);
  scatter_k<<<(S_TOK+255)/256, 256, 0, stream>>>(idx, scr, hdr, slot_of, tok_slot, scr_slot);
  gemm1_k  <<<dim3(FFN_/64,  S_TOK/128, NEXP), 256, 0, stream>>>(X, W1, hdr, tok_slot, inter);
  gemm2_k  <<<dim3(HID/128,  S_TOK/128, NEXP), 256, 0, stream>>>(inter, W2, hdr, scr_slot, eout);
  combine_k<<<S_TOK, 256, 0, stream>>>(eout, slot_of, out);
}